// Round 1
// baseline (1902.963 us; speedup 1.0000x reference)
//
#include <hip/hip_runtime.h>
#include <stdint.h>

#define BB 8
#define NN 65536
#define GG 512
#define MM 64
#define STEPS 63          // GROUP_SIZE - 1
#define NWALK (BB*GG)     // 4096

// ---------------- threefry2x32 (JAX-exact, 20 rounds) ----------------
__device__ __forceinline__ uint32_t rotl32(uint32_t x, uint32_t r){ return (x<<r)|(x>>(32u-r)); }

__device__ __forceinline__ void tf2x32(uint32_t k0, uint32_t k1, uint32_t x0, uint32_t x1,
                                       uint32_t &o0, uint32_t &o1){
  const uint32_t ks2 = k0 ^ k1 ^ 0x1BD11BDAu;
  x0 += k0; x1 += k1;
#define TFR(r) { x0 += x1; x1 = rotl32(x1,(r)); x1 ^= x0; }
  TFR(13) TFR(15) TFR(26) TFR(6)
  x0 += k1;  x1 += ks2 + 1u;
  TFR(17) TFR(29) TFR(16) TFR(24)
  x0 += ks2; x1 += k0 + 2u;
  TFR(13) TFR(15) TFR(26) TFR(6)
  x0 += k0;  x1 += k1 + 3u;
  TFR(17) TFR(29) TFR(16) TFR(24)
  x0 += k1;  x1 += ks2 + 4u;
  TFR(13) TFR(15) TFR(26) TFR(6)
  x0 += ks2; x1 += k0 + 5u;
#undef TFR
  o0 = x0; o1 = x1;
}

// ---------------- kernel A: PRNG table (partitionable threefry) + sync-slot init ----------------
// Per (walk, step): 3 uniform floats (pre-or'd bits) + rnd int. Layout [step][walk] for coalescing.
__global__ void rng_init_kernel(uint4* __restrict__ rng,
                                unsigned long long* __restrict__ slots,
                                int* __restrict__ center_idx){
  int tid = blockIdx.x*blockDim.x + threadIdx.x;
  if (tid < 511*BB*4) slots[tid] = 0ull;          // FPS sync slots, zeroed every call
  if (tid < BB) center_idx[tid*GG] = 0;           // FPS start index = 0
  if (tid >= STEPS*NWALK) return;
  int step = tid / NWALK;
  int walk = tid - step*NWALK;
  uint32_t kj0,kj1,t0,t1,a0,a1,b0,b1,p0,p1,q0,q1,r0,r1,l0,l1;
  // keys = split(key(42)=(0,42), 4096): key_j = TF(master, (0, j))
  tf2x32(0u, 42u, 0u, (uint32_t)walk, kj0, kj1);
  // step keys = split(key_j, 63): kk_i = TF(key_j, (0, i))
  tf2x32(kj0, kj1, 0u, (uint32_t)step, t0, t1);
  // ka, kb = split(kk, 2)
  tf2x32(t0, t1, 0u, 0u, a0, a1);
  tf2x32(t0, t1, 0u, 1u, b0, b1);
  // uniform(ka, (3,)): bits_i = y0^y1 of TF(ka, (0,i))
  tf2x32(a0, a1, 0u, 0u, p0, p1);
  tf2x32(a0, a1, 0u, 1u, q0, q1);
  tf2x32(a0, a1, 0u, 2u, r0, r1);
  // randint(kb, (), 0, 65536): lower_bits = y0^y1 of TF(kb, (0,1)); span=2^16 -> & 0xFFFF
  tf2x32(b0, b1, 0u, 1u, l0, l1);
  uint4 e;
  e.x = ((p0 ^ p1) >> 9) | 0x3f800000u;
  e.y = ((q0 ^ q1) >> 9) | 0x3f800000u;
  e.z = ((r0 ^ r1) >> 9) | 0x3f800000u;
  e.w = (l0 ^ l1) & 0xFFFFu;
  rng[tid] = e;
}

// ---------------- kernel B: farthest point sampling ----------------
// 8 batches x 4 blocks x 1024 threads; 16 points/thread fully register-resident.
// Cross-block argmax per iteration: each block release-stores its packed best
// (dist_bits<<32 | ~idx) to its slot, then polls the other 3 (acquire).
#define FPK 4
#define FPT 1024
#define PPT 16

__global__ __launch_bounds__(FPT) void fps_kernel(const float* __restrict__ xyz,
                                                  unsigned long long* __restrict__ slots,
                                                  int* __restrict__ center_idx){
  int b = blockIdx.x & 7;        // batch -> same XCD for all 4 blocks of a batch (perf only)
  int k = blockIdx.x >> 3;       // shard 0..3
  int t = threadIdx.x;
  const float* bx = xyz + (size_t)b*NN*3;
  float px[PPT], py[PPT], pz[PPT], dd[PPT];
  const int base = k*(FPT*PPT);
#pragma unroll
  for(int q=0;q<PPT;q++){
    int gi = base + q*FPT + t;
    px[q]=bx[3*gi]; py[q]=bx[3*gi+1]; pz[q]=bx[3*gi+2];
    dd[q]=1e10f;
  }
  __shared__ unsigned long long lred[FPT/64];
  __shared__ unsigned int lwin;
  float cx = bx[0], cy = bx[1], cz = bx[2];   // start point = index 0
  for(int it=1; it<GG; ++it){
    unsigned long long best = 0ull;
#pragma unroll
    for(int q=0;q<PPT;q++){
      // match XLA: uncontracted mul/add, sum order ((dx^2+dy^2)+dz^2)
      float dx = __fadd_rn(px[q], -cx);
      float dy = __fadd_rn(py[q], -cy);
      float dz = __fadd_rn(pz[q], -cz);
      float d  = __fmul_rn(dx,dx);
      d = __fadd_rn(d, __fmul_rn(dy,dy));
      d = __fadd_rn(d, __fmul_rn(dz,dz));
      float nd = fminf(dd[q], d);
      dd[q] = nd;
      int gi = base + q*FPT + t;
      unsigned long long key = ((unsigned long long)__float_as_uint(nd) << 32) | (unsigned int)(~gi);
      best = key > best ? key : best;
    }
#pragma unroll
    for(int off=32; off; off>>=1){
      unsigned long long o = __shfl_xor(best, off, 64);
      best = o > best ? o : best;
    }
    if ((t & 63)==0) lred[t>>6] = best;
    __syncthreads();
    if (t==0){
      unsigned long long bb = lred[0];
#pragma unroll
      for(int w=1;w<FPT/64;w++){ unsigned long long o=lred[w]; bb = o>bb?o:bb; }
      unsigned long long* slot = slots + ((size_t)(it-1)*BB + b)*FPK;
      __hip_atomic_store(&slot[k], bb, __ATOMIC_RELEASE, __HIP_MEMORY_SCOPE_AGENT);
      unsigned long long all = bb;
      for(int j=0;j<FPK;j++){
        if (j==k) continue;
        unsigned long long v;
        do { v = __hip_atomic_load(&slot[j], __ATOMIC_ACQUIRE, __HIP_MEMORY_SCOPE_AGENT); } while (v==0ull);
        all = v>all?v:all;
      }
      unsigned int widx = (unsigned int)(~(unsigned int)all);
      if (k==0) center_idx[b*GG + it] = (int)widx;
      lwin = widx;
    }
    __syncthreads();
    unsigned int w = lwin;
    cx = bx[3*w]; cy = bx[3*w+1]; cz = bx[3*w+2];
  }
}

// ---------------- kernel C: random walks + all outputs ----------------
// One thread per walk; visited set = private 128-slot linear-probe hash in LDS.
#define WBLK 64
__global__ __launch_bounds__(WBLK) void walk_kernel(const float* __restrict__ xyz,
                                                    const int* __restrict__ ring,
                                                    const uint4* __restrict__ rng,
                                                    const int* __restrict__ center_idx,
                                                    float* __restrict__ out){
  __shared__ uint32_t hashv[128*WBLK];   // [slot][thread], 32 KiB
  const int t = threadIdx.x;
  for(int i=0;i<128;i++) hashv[i*WBLK + t] = 0u;   // private columns, no barrier needed

  const int walk = blockIdx.x*WBLK + t;
  const int b = walk >> 9;
  const float* bx = xyz + (size_t)b*NN*3;
  const int*  br = ring + (size_t)b*NN*3;

  float* out_nb = out;                            // [NWALK][64][3]
  float* out_c  = out + (size_t)NWALK*MM*3;       // [NWALK][3]
  float* out_i  = out_c + (size_t)NWALK*3;        // [NWALK][64]

  const int cidx = center_idx[walk];
  const float cx = bx[3*cidx], cy = bx[3*cidx+1], cz = bx[3*cidx+2];
  out_c[walk*3+0]=cx; out_c[walk*3+1]=cy; out_c[walk*3+2]=cz;
  out_i[(size_t)walk*MM] = (float)cidx;
  { size_t o = (size_t)walk*MM*3; out_nb[o]=0.0f; out_nb[o+1]=0.0f; out_nb[o+2]=0.0f; }

  auto ins = [&](uint32_t v){
    uint32_t h = (v*2654435761u) >> 25;
    for(;;){ uint32_t c = hashv[h*WBLK+t];
             if (c==v+1u) return;
             if (c==0u){ hashv[h*WBLK+t]=v+1u; return; }
             h=(h+1u)&127u; }
  };
  auto has = [&](uint32_t v)->bool{
    uint32_t h = (v*2654435761u) >> 25;
    for(;;){ uint32_t c = hashv[h*WBLK+t];
             if (c==0u) return false;
             if (c==v+1u) return true;
             h=(h+1u)&127u; }
  };

  ins((uint32_t)cidx);
  int cur = cidx;
  for(int i=0;i<STEPS;i++){
    int n0 = br[3*cur], n1 = br[3*cur+1], n2 = br[3*cur+2];
    bool m0 = !has((uint32_t)n0), m1 = !has((uint32_t)n1), m2 = !has((uint32_t)n2);
    uint4 e = rng[(size_t)i*NWALK + walk];
    float s0 = m0 ? __fadd_rn(__uint_as_float(e.x), -1.0f) : -1.0f;
    float s1 = m1 ? __fadd_rn(__uint_as_float(e.y), -1.0f) : -1.0f;
    float s2 = m2 ? __fadd_rn(__uint_as_float(e.z), -1.0f) : -1.0f;
    // first-max-wins argmax over 3 (matches jnp.argmax)
    int pick = n0; float sb = s0;
    if (s1 > sb){ sb=s1; pick=n1; }
    if (s2 > sb){ sb=s2; pick=n2; }
    int nxt = (m0||m1||m2) ? pick : (int)e.w;
    ins((uint32_t)nxt);
    out_i[(size_t)walk*MM + i+1] = (float)nxt;
    float vx = __fadd_rn(bx[3*nxt],   -cx);
    float vy = __fadd_rn(bx[3*nxt+1], -cy);
    float vz = __fadd_rn(bx[3*nxt+2], -cz);
    size_t o = ((size_t)walk*MM + (size_t)(i+1))*3;
    out_nb[o]=vx; out_nb[o+1]=vy; out_nb[o+2]=vz;
    cur = nxt;
  }
}

// ---------------- launcher ----------------
extern "C" void kernel_launch(void* const* d_in, const int* in_sizes, int n_in,
                              void* d_out, int out_size, void* d_ws, size_t ws_size,
                              hipStream_t stream) {
  const float* xyz  = (const float*)d_in[0];
  const int*   ring = (const int*)d_in[1];
  // d_in[2] (vertices) and d_in[3] (faces) are unused by the reference.

  // workspace layout
  unsigned long long* slots = (unsigned long long*)d_ws;                 // 511*8*4*8 = 130816 B
  int*   center_idx = (int*)((char*)d_ws + 131072);                      // 4096*4   = 16384 B
  uint4* rng        = (uint4*)((char*)d_ws + 131072 + 16384);            // 258048*16 = 4128768 B
  float* out        = (float*)d_out;

  hipLaunchKernelGGL(rng_init_kernel, dim3((STEPS*NWALK)/256), dim3(256), 0, stream,
                     rng, slots, center_idx);
  hipLaunchKernelGGL(fps_kernel, dim3(BB*FPK), dim3(FPT), 0, stream,
                     xyz, slots, center_idx);
  hipLaunchKernelGGL(walk_kernel, dim3(NWALK/WBLK), dim3(WBLK), 0, stream,
                     xyz, ring, rng, center_idx, out);
}

// Round 2
// 1235.908 us; speedup vs baseline: 1.5397x; 1.5397x over previous
//
#include <hip/hip_runtime.h>
#include <stdint.h>

#define BB 8
#define NN 65536
#define GG 512
#define MM 64
#define STEPS 63          // GROUP_SIZE - 1
#define NWALK (BB*GG)     // 4096

#define FPK 16            // blocks per batch
#define FPT 1024          // threads per FPS block
#define PPT (NN/(FPK*FPT))// 4 points per thread
#define SLOTN (511*BB*FPK)// 65408 sync slots

// ---------------- threefry2x32 (JAX-exact, 20 rounds) ----------------
__device__ __forceinline__ uint32_t rotl32(uint32_t x, uint32_t r){ return (x<<r)|(x>>(32u-r)); }

__device__ __forceinline__ void tf2x32(uint32_t k0, uint32_t k1, uint32_t x0, uint32_t x1,
                                       uint32_t &o0, uint32_t &o1){
  const uint32_t ks2 = k0 ^ k1 ^ 0x1BD11BDAu;
  x0 += k0; x1 += k1;
#define TFR(r) { x0 += x1; x1 = rotl32(x1,(r)); x1 ^= x0; }
  TFR(13) TFR(15) TFR(26) TFR(6)
  x0 += k1;  x1 += ks2 + 1u;
  TFR(17) TFR(29) TFR(16) TFR(24)
  x0 += ks2; x1 += k0 + 2u;
  TFR(13) TFR(15) TFR(26) TFR(6)
  x0 += k0;  x1 += k1 + 3u;
  TFR(17) TFR(29) TFR(16) TFR(24)
  x0 += k1;  x1 += ks2 + 4u;
  TFR(13) TFR(15) TFR(26) TFR(6)
  x0 += ks2; x1 += k0 + 5u;
#undef TFR
  o0 = x0; o1 = x1;
}

// ---------------- kernel A: PRNG table (partitionable threefry) + sync-slot init ----------------
__global__ void rng_init_kernel(uint4* __restrict__ rng,
                                unsigned long long* __restrict__ slots,
                                int* __restrict__ center_idx){
  int tid = blockIdx.x*blockDim.x + threadIdx.x;
  if (tid < SLOTN) slots[tid] = 0ull;             // FPS sync slots, zeroed every call
  if (tid < BB) center_idx[tid*GG] = 0;           // FPS start index = 0
  if (tid >= STEPS*NWALK) return;
  int step = tid / NWALK;
  int walk = tid - step*NWALK;
  uint32_t kj0,kj1,t0,t1,a0,a1,b0,b1,p0,p1,q0,q1,r0,r1,l0,l1;
  tf2x32(0u, 42u, 0u, (uint32_t)walk, kj0, kj1);  // key_j = TF(master(0,42), (0,j))
  tf2x32(kj0, kj1, 0u, (uint32_t)step, t0, t1);   // step key
  tf2x32(t0, t1, 0u, 0u, a0, a1);                 // ka
  tf2x32(t0, t1, 0u, 1u, b0, b1);                 // kb
  tf2x32(a0, a1, 0u, 0u, p0, p1);                 // uniform bits
  tf2x32(a0, a1, 0u, 1u, q0, q1);
  tf2x32(a0, a1, 0u, 2u, r0, r1);
  tf2x32(b0, b1, 0u, 1u, l0, l1);                 // randint lower bits
  uint4 e;
  e.x = ((p0 ^ p1) >> 9) | 0x3f800000u;
  e.y = ((q0 ^ q1) >> 9) | 0x3f800000u;
  e.z = ((r0 ^ r1) >> 9) | 0x3f800000u;
  e.w = (l0 ^ l1) & 0xFFFFu;
  rng[tid] = e;
}

// ---------------- kernel B: farthest point sampling ----------------
// 8 batches x 16 blocks x 1024 threads; 4 points/thread register-resident.
// Cross-block argmax via relaxed agent-scope slots: lane k stores own best,
// lanes 0..15 poll all 16 slots IN PARALLEL (value IS the payload -> no fences).
__global__ __launch_bounds__(FPT) void fps_kernel(const float* __restrict__ xyz,
                                                  unsigned long long* __restrict__ slots,
                                                  int* __restrict__ center_idx){
  const int b = blockIdx.x & 7;    // batch (round-robin XCD: batch-mates spread, sync via MALL anyway)
  const int k = blockIdx.x >> 3;   // shard 0..15
  const int t = threadIdx.x;
  const float* bx = xyz + (size_t)b*NN*3;
  float px[PPT], py[PPT], pz[PPT], dd[PPT];
  unsigned int nig[PPT];
  const int base = k*(FPT*PPT);
#pragma unroll
  for(int q=0;q<PPT;q++){
    int gi = base + q*FPT + t;
    px[q]=bx[3*gi]; py[q]=bx[3*gi+1]; pz[q]=bx[3*gi+2];
    dd[q]=1e10f; nig[q]=~(unsigned int)gi;
  }
  __shared__ unsigned long long lred[FPT/64];
  __shared__ unsigned int lwin;
  float cx = bx[0], cy = bx[1], cz = bx[2];   // start point = index 0
  for(int it=1; it<GG; ++it){
    unsigned long long best = 0ull;
#pragma unroll
    for(int q=0;q<PPT;q++){
      // match XLA: uncontracted mul/add, sum order ((dx^2+dy^2)+dz^2)
      float dx = __fadd_rn(px[q], -cx);
      float dy = __fadd_rn(py[q], -cy);
      float dz = __fadd_rn(pz[q], -cz);
      float d  = __fmul_rn(dx,dx);
      d = __fadd_rn(d, __fmul_rn(dy,dy));
      d = __fadd_rn(d, __fmul_rn(dz,dz));
      float nd = fminf(dd[q], d);
      dd[q] = nd;
      unsigned long long key = ((unsigned long long)__float_as_uint(nd) << 32) | nig[q];
      best = key > best ? key : best;
    }
#pragma unroll
    for(int off=32; off; off>>=1){
      unsigned long long o = __shfl_xor(best, off, 64);
      best = o > best ? o : best;
    }
    if ((t & 63)==0) lred[t>>6] = best;
    __syncthreads();
    if (t < 64){
      // block-level reduce: lanes 0..15 pick up per-wave maxima
      unsigned long long v = (t < FPT/64) ? lred[t] : 0ull;
#pragma unroll
      for(int off=32; off; off>>=1){
        unsigned long long o = __shfl_xor(v, off, 64);
        v = o > v ? o : v;                 // all 64 lanes now hold block best
      }
      unsigned long long* slot = slots + ((size_t)(it-1)*BB + b)*FPK;
      if (t==0)
        __hip_atomic_store(&slot[k], v, __ATOMIC_RELAXED, __HIP_MEMORY_SCOPE_AGENT);
      // parallel poll: lane j waits on slot j (own slot short-circuited)
      unsigned long long sv = v;
      if (t < FPK && t != k){
        do { sv = __hip_atomic_load(&slot[t], __ATOMIC_RELAXED, __HIP_MEMORY_SCOPE_AGENT); }
        while (sv == 0ull);
      }
      if (t >= FPK) sv = 0ull;
#pragma unroll
      for(int off=8; off; off>>=1){
        unsigned long long o = __shfl_xor(sv, off, 64);
        sv = o > sv ? o : sv;              // max over the 16 slots
      }
      if (t==0){
        unsigned int widx = ~(unsigned int)sv;
        lwin = widx;
        if (k==0) center_idx[b*GG + it] = (int)widx;
      }
    }
    __syncthreads();
    unsigned int w = lwin;
    cx = bx[3*w]; cy = bx[3*w+1]; cz = bx[3*w+2];
  }
}

// ---------------- kernel C: random walks + all outputs ----------------
#define WBLK 64
__global__ __launch_bounds__(WBLK) void walk_kernel(const float* __restrict__ xyz,
                                                    const int* __restrict__ ring,
                                                    const uint4* __restrict__ rng,
                                                    const int* __restrict__ center_idx,
                                                    float* __restrict__ out){
  __shared__ uint32_t hashv[128*WBLK];   // [slot][thread], 32 KiB
  const int t = threadIdx.x;
  for(int i=0;i<128;i++) hashv[i*WBLK + t] = 0u;   // private columns, no barrier needed

  const int walk = blockIdx.x*WBLK + t;
  const int b = walk >> 9;
  const float* bx = xyz + (size_t)b*NN*3;
  const int*  br = ring + (size_t)b*NN*3;

  float* out_nb = out;                            // [NWALK][64][3]
  float* out_c  = out + (size_t)NWALK*MM*3;       // [NWALK][3]
  float* out_i  = out_c + (size_t)NWALK*3;        // [NWALK][64]

  const int cidx = center_idx[walk];
  const float cx = bx[3*cidx], cy = bx[3*cidx+1], cz = bx[3*cidx+2];
  out_c[walk*3+0]=cx; out_c[walk*3+1]=cy; out_c[walk*3+2]=cz;
  out_i[(size_t)walk*MM] = (float)cidx;
  { size_t o = (size_t)walk*MM*3; out_nb[o]=0.0f; out_nb[o+1]=0.0f; out_nb[o+2]=0.0f; }

  auto ins = [&](uint32_t v){
    uint32_t h = (v*2654435761u) >> 25;
    for(;;){ uint32_t c = hashv[h*WBLK+t];
             if (c==v+1u) return;
             if (c==0u){ hashv[h*WBLK+t]=v+1u; return; }
             h=(h+1u)&127u; }
  };
  auto has = [&](uint32_t v)->bool{
    uint32_t h = (v*2654435761u) >> 25;
    for(;;){ uint32_t c = hashv[h*WBLK+t];
             if (c==0u) return false;
             if (c==v+1u) return true;
             h=(h+1u)&127u; }
  };

  ins((uint32_t)cidx);
  int cur = cidx;
  for(int i=0;i<STEPS;i++){
    int n0 = br[3*cur], n1 = br[3*cur+1], n2 = br[3*cur+2];
    bool m0 = !has((uint32_t)n0), m1 = !has((uint32_t)n1), m2 = !has((uint32_t)n2);
    uint4 e = rng[(size_t)i*NWALK + walk];
    float s0 = m0 ? __fadd_rn(__uint_as_float(e.x), -1.0f) : -1.0f;
    float s1 = m1 ? __fadd_rn(__uint_as_float(e.y), -1.0f) : -1.0f;
    float s2 = m2 ? __fadd_rn(__uint_as_float(e.z), -1.0f) : -1.0f;
    int pick = n0; float sb = s0;
    if (s1 > sb){ sb=s1; pick=n1; }
    if (s2 > sb){ sb=s2; pick=n2; }
    int nxt = (m0||m1||m2) ? pick : (int)e.w;
    ins((uint32_t)nxt);
    out_i[(size_t)walk*MM + i+1] = (float)nxt;
    float vx = __fadd_rn(bx[3*nxt],   -cx);
    float vy = __fadd_rn(bx[3*nxt+1], -cy);
    float vz = __fadd_rn(bx[3*nxt+2], -cz);
    size_t o = ((size_t)walk*MM + (size_t)(i+1))*3;
    out_nb[o]=vx; out_nb[o+1]=vy; out_nb[o+2]=vz;
    cur = nxt;
  }
}

// ---------------- launcher ----------------
extern "C" void kernel_launch(void* const* d_in, const int* in_sizes, int n_in,
                              void* d_out, int out_size, void* d_ws, size_t ws_size,
                              hipStream_t stream) {
  const float* xyz  = (const float*)d_in[0];
  const int*   ring = (const int*)d_in[1];

  // workspace layout
  unsigned long long* slots = (unsigned long long*)d_ws;                 // 65408*8 = 523264 B
  int*   center_idx = (int*)((char*)d_ws + 524288);                      // 4096*4  = 16384 B
  uint4* rng        = (uint4*)((char*)d_ws + 524288 + 16384);            // 258048*16 B
  float* out        = (float*)d_out;

  hipLaunchKernelGGL(rng_init_kernel, dim3((STEPS*NWALK)/256), dim3(256), 0, stream,
                     rng, slots, center_idx);
  hipLaunchKernelGGL(fps_kernel, dim3(BB*FPK), dim3(FPT), 0, stream,
                     xyz, slots, center_idx);
  hipLaunchKernelGGL(walk_kernel, dim3(NWALK/WBLK), dim3(WBLK), 0, stream,
                     xyz, ring, rng, center_idx, out);
}